// Round 8
// baseline (210.422 us; speedup 1.0000x reference)
//
#include <hip/hip_runtime.h>
#include <hip/hip_bf16.h>

typedef __bf16 bf16_t;
typedef __bf16 bf16x8 __attribute__((ext_vector_type(8)));
typedef _Float16 f16x4 __attribute__((ext_vector_type(4)));
typedef _Float16 f16x8 __attribute__((ext_vector_type(8)));
typedef float f32x4 __attribute__((ext_vector_type(4)));

#define SEQ    2048
#define NH     16
#define HD     64
#define HIDDEN 1024
#define LOG2E  1.44269504f
#define CSTR   41   // combine overlay stride (odd -> bank-permuting)

__device__ __forceinline__ bf16_t to_bf16(float f) { return (bf16_t)f; }

// async 16B global->LDS DMA; LDS dest is wave-uniform base, HW adds lane*16.
__device__ __forceinline__ void async16(const void* g, void* l) {
    __builtin_amdgcn_global_load_lds((const __attribute__((address_space(1))) void*)g,
                                     (__attribute__((address_space(3))) void*)l, 16, 0, 0);
}

// ---------------- fp32 -> bf16 convert (5 segments, one launch) ----------------
__global__ __launch_bounds__(256) void cvt_kernel(
    const float* __restrict__ s0, bf16_t* __restrict__ d0, int c0,
    const float* __restrict__ s1, bf16_t* __restrict__ d1, int c1,
    const float* __restrict__ s2, bf16_t* __restrict__ d2, int c2,
    const float* __restrict__ s3, bf16_t* __restrict__ d3, int c3,
    const float* __restrict__ s4, bf16_t* __restrict__ d4, int c4)
{
    int blk = blockIdx.x;
    const float* s; bf16_t* d;
    if (blk < c0)              { s = s0; d = d0; }
    else if ((blk -= c0) < c1) { s = s1; d = d1; }
    else if ((blk -= c1) < c2) { s = s2; d = d2; }
    else if ((blk -= c2) < c3) { s = s3; d = d3; }
    else                       { blk -= c3; s = s4; d = d4; }
    const size_t base = (size_t)blk * 2048 + threadIdx.x * 8;
    const float4 a = *(const float4*)&s[base];
    const float4 b = *(const float4*)&s[base + 4];
    bf16x8 o;
    o[0] = (bf16_t)a.x; o[1] = (bf16_t)a.y; o[2] = (bf16_t)a.z; o[3] = (bf16_t)a.w;
    o[4] = (bf16_t)b.x; o[5] = (bf16_t)b.y; o[6] = (bf16_t)b.z; o[7] = (bf16_t)b.w;
    *(bf16x8*)&d[base] = o;
}

// ---------------- QKV projection: 128x128 tile, BK=64, LDS-staged epilogue ----
// z=0:Q, z=1:K -> [B,S,1024] bf16; z=2:V -> [B,H,64,S] fp16 (PV B-operand)
__global__ __launch_bounds__(256, 3) void qkv_kernel(
    const bf16_t* __restrict__ X,
    const bf16_t* __restrict__ wq, const bf16_t* __restrict__ wk, const bf16_t* __restrict__ wv,
    const float* __restrict__ bq, const float* __restrict__ bk, const float* __restrict__ bv,
    bf16_t* __restrict__ qws, bf16_t* __restrict__ kws, _Float16* __restrict__ vws)
{
    __shared__ __align__(16) bf16_t Sh[2 * 128 * 64];   // As|Bs; reused as epilogue tile
    bf16_t* As = Sh;
    bf16_t* Bs = Sh + 128 * 64;
    const int z = blockIdx.z;
    const bf16_t* Wsel = (z == 0) ? wq : (z == 1) ? wk : wv;
    const float*  bsel = (z == 0) ? bq : (z == 1) ? bk : bv;
    const int m0 = blockIdx.y * 128, n0 = blockIdx.x * 128;

    const int t = threadIdx.x, lane = t & 63, w = t >> 6;
    const int w0 = w & 1, w1 = w >> 1, l15 = lane & 15, q4 = lane >> 4;

    f32x4 acc[4][4];
#pragma unroll
    for (int i = 0; i < 4; i++)
#pragma unroll
        for (int j = 0; j < 4; j++) acc[i][j] = f32x4{0.f, 0.f, 0.f, 0.f};

    for (int kt = 0; kt < HIDDEN; kt += 64) {
#pragma unroll
        for (int j = 0; j < 4; j++) {
            const int s = j * 256 + t;              // 16B slot 0..1023
            const int row = s >> 3, c = (s & 7) ^ (row & 7);
            const int lbase = (j * 256 + w * 64) * 8;
            async16(&X[(size_t)(m0 + row) * HIDDEN + kt + c * 8], &As[lbase]);
            async16(&Wsel[(size_t)(n0 + row) * HIDDEN + kt + c * 8], &Bs[lbase]);
        }
        __syncthreads();
#pragma unroll
        for (int ks = 0; ks < 2; ks++) {
            bf16x8 af[4];
#pragma unroll
            for (int ti = 0; ti < 4; ti++) {
                const int ra = w0 * 64 + ti * 16 + l15;
                af[ti] = *(const bf16x8*)&As[ra * 64 + (((ks * 4 + q4) ^ (ra & 7))) * 8];
            }
#pragma unroll
            for (int tj = 0; tj < 4; tj++) {
                const int rb = w1 * 64 + tj * 16 + l15;
                const bf16x8 bfr = *(const bf16x8*)&Bs[rb * 64 + (((ks * 4 + q4) ^ (rb & 7))) * 8];
#pragma unroll
                for (int ti = 0; ti < 4; ti++)
                    acc[ti][tj] = __builtin_amdgcn_mfma_f32_16x16x32_bf16(af[ti], bfr, acc[ti][tj], 0, 0, 0);
            }
        }
        __syncthreads();
    }

    // ---- epilogue: acc -> LDS tile (swizzled) -> coalesced b128 stores ----
    if (z < 2) {
        // LDS [m][n] bf16 128x128; chunk(8 elems) XOR-swizzled by m
#pragma unroll
        for (int tj = 0; tj < 4; tj++) {
            const int n = w1 * 64 + tj * 16 + l15;
            const float bb = bsel[n0 + n];
            const int ch = (n >> 3), sub = n & 7;
#pragma unroll
            for (int ti = 0; ti < 4; ti++)
#pragma unroll
                for (int r = 0; r < 4; r++) {
                    const int m = w0 * 64 + ti * 16 + q4 * 4 + r;
                    Sh[m * 128 + ((ch ^ (m & 15)) << 3) + sub] = to_bf16(acc[ti][tj][r] + bb);
                }
        }
        __syncthreads();
        bf16_t* dst = (z == 0) ? qws : kws;
#pragma unroll
        for (int i = 0; i < 8; i++) {
            const int g = i * 256 + t;
            const int row = g >> 4, c = g & 15;
            const bf16x8 vv = *(const bf16x8*)&Sh[row * 128 + ((c ^ (row & 15)) << 3)];
            *(bf16x8*)&dst[(size_t)(m0 + row) * HIDDEN + n0 + c * 8] = vv;
        }
    } else {
        // LDS [n(d)][m(s)] f16 128x128 (transpose in LDS)
        _Float16* Vt = (_Float16*)Sh;
#pragma unroll
        for (int tj = 0; tj < 4; tj++) {
            const int n = w1 * 64 + tj * 16 + l15;
            const float bb = bsel[n0 + n];
#pragma unroll
            for (int ti = 0; ti < 4; ti++) {
                const int mb = w0 * 64 + ti * 16 + q4 * 4;
                f16x4 v;
#pragma unroll
                for (int r = 0; r < 4; r++) v[r] = (_Float16)(acc[ti][tj][r] + bb);
                *(f16x4*)&Vt[n * 128 + (((mb >> 3) ^ (n & 15)) << 3) + (mb & 7)] = v;
            }
        }
        __syncthreads();
        const int b = m0 >> 11, sbase = m0 & (SEQ - 1);
#pragma unroll
        for (int i = 0; i < 8; i++) {
            const int g = i * 256 + t;
            const int row = g >> 4, c = g & 15;       // row = d-col, c = s-chunk
            const f16x8 vv = *(const f16x8*)&Vt[row * 128 + ((c ^ (row & 15)) << 3)];
            const int d = (n0 + row) & 63, hh = (n0 + row) >> 6;
            *(f16x8*)&vws[(((size_t)b * NH + hh) * HD + d) * SEQ + sbase + c * 8] = vv;
        }
    }
}

// ---------------- flash attention: S^T registers, DOUBLE-BUFFERED K/V --------
// grid 1024: 32 bh x 32 q-tiles(64). Block 256 = 4 waves:
// wave w: q-sub (w&1)*32, K-half (w>>1)*1024. One barrier/iter; DMA for it+1
// issued right after the barrier -> drain at next barrier is ~free.
__global__ __launch_bounds__(256, 2) void attn_kernel(
    const bf16_t* __restrict__ Qw, const bf16_t* __restrict__ Kw,
    const _Float16* __restrict__ Vtw, const float* __restrict__ Mask,
    bf16_t* __restrict__ Ow)
{
    __shared__ __align__(16) bf16_t Tiles[2][2][2][64 * 64];   // [dbuf][khalf][K|V] 64 KB

    const int t = threadIdx.x, lane = t & 63, w = t >> 6;
    const int l15 = lane & 15, q4 = lane >> 4;
    const int wq = w & 1, kh = w >> 1;
    // XCD swizzle: cluster 4 heads per XCD (K/V fit per-XCD L2)
    const int lid = blockIdx.x;
    const int c8 = lid & 7, j = lid >> 3;
    const int bh = c8 * 4 + (j >> 5);
    const int q0 = (j & 31) * 64;
    const int b = bh >> 4, h = bh & 15;

    const bf16_t* Qh = Qw + (size_t)b * SEQ * HIDDEN + h * HD;     // [s][1024]
    const bf16_t* Kh = Kw + (size_t)b * SEQ * HIDDEN + h * HD;
    const _Float16* Vh = Vtw + (size_t)bh * HD * SEQ;              // [64][SEQ]
    const float* Mrow = Mask + (size_t)b * SEQ;

    bf16x8 qf[2][2];
#pragma unroll
    for (int nq = 0; nq < 2; nq++)
#pragma unroll
        for (int ks = 0; ks < 2; ks++)
            qf[nq][ks] = *(const bf16x8*)&Qh[(size_t)(q0 + wq * 32 + nq * 16 + l15) * HIDDEN + ks * 32 + q4 * 8];

    f32x4 oacc[2][4];
#pragma unroll
    for (int nq = 0; nq < 2; nq++)
#pragma unroll
        for (int nb = 0; nb < 4; nb++) oacc[nq][nb] = f32x4{0.f, 0.f, 0.f, 0.f};
    f32x4 pacc[2] = {f32x4{0.f, 0.f, 0.f, 0.f}, f32x4{0.f, 0.f, 0.f, 0.f}};
    const f16x4 vones = {(_Float16)1.f, (_Float16)1.f, (_Float16)1.f, (_Float16)1.f};

    const int kbase = kh * (SEQ / 2);
    // staging addresses (lane-dependent parts are loop-invariant)
    const int s0_ = wq * 64 + lane;                 // slot within wave-pair quarter

    // stage(it, buf): 4 chunks of K + 4 of V per wave-pair half
    auto stage = [&](int it, int buf) {
        const int kt = kbase + it * 64;
        bf16_t* Ksh = &Tiles[buf][kh][0][0];
        _Float16* Vsh = (_Float16*)&Tiles[buf][kh][1][0];
#pragma unroll
        for (int jj = 0; jj < 4; jj++) {
            const int s = jj * 128 + s0_;
            const int row = s >> 3, c = (s & 7) ^ (row & 7);
            const int lbase = (jj * 128 + wq * 64) * 8;
            async16(&Kh[(size_t)(kt + row) * HIDDEN + c * 8], &Ksh[lbase]);
            async16(&Vh[(size_t)row * SEQ + kt + c * 8], &Vsh[lbase]);
        }
    };

    stage(0, 0);

    for (int it = 0; it < 16; it++) {
        const int cur = it & 1;
        __syncthreads();                 // buf[cur] ready; buf[cur^1] free
        if (it < 15) stage(it + 1, cur ^ 1);

        const bf16_t* Ksh = &Tiles[cur][kh][0][0];
        const _Float16* Vsh = (const _Float16*)&Tiles[cur][kh][1][0];
        const int kt = kbase + it * 64;

        // S^T = K Q^T: lane(l15=q, q4) reg r -> kpos = cb*16 + q4*4 + r
        f32x4 sa[2][4];
#pragma unroll
        for (int nq = 0; nq < 2; nq++)
#pragma unroll
            for (int cb = 0; cb < 4; cb++) sa[nq][cb] = f32x4{0.f, 0.f, 0.f, 0.f};
#pragma unroll
        for (int cb = 0; cb < 4; cb++)
#pragma unroll
            for (int ks = 0; ks < 2; ks++) {
                const int rk = cb * 16 + l15;
                const bf16x8 kf = *(const bf16x8*)&Ksh[rk * 64 + (((ks * 4 + q4) ^ (rk & 7))) * 8];
                sa[0][cb] = __builtin_amdgcn_mfma_f32_16x16x32_bf16(kf, qf[0][ks], sa[0][cb], 0, 0, 0);
                sa[1][cb] = __builtin_amdgcn_mfma_f32_16x16x32_bf16(kf, qf[1][ks], sa[1][cb], 0, 0, 0);
            }

        // softmax numerator in-register
        f16x4 ph[2][4];
#pragma unroll
        for (int cb = 0; cb < 4; cb++) {
            float4 mv = *(const float4*)&Mrow[kt + cb * 16 + q4 * 4];
            mv.x *= LOG2E; mv.y *= LOG2E; mv.z *= LOG2E; mv.w *= LOG2E;
            const float mk[4] = {mv.x, mv.y, mv.z, mv.w};
#pragma unroll
            for (int nq = 0; nq < 2; nq++) {
#pragma unroll
                for (int r = 0; r < 4; r++)
                    ph[nq][cb][r] = (_Float16)exp2f(fmaf(sa[nq][cb][r], 0.125f * LOG2E, mk[r]));
            }
        }

        // PV + row-sum (ones column): P registers are A-operand of 16x16x16f16
#pragma unroll
        for (int cb = 0; cb < 4; cb++) {
#pragma unroll
            for (int nb = 0; nb < 4; nb++) {
                const int rv = nb * 16 + l15;
                const int cl = (cb * 2 + (q4 >> 1)) ^ (rv & 7);
                const f16x4 vf = *(const f16x4*)&Vsh[rv * 64 + cl * 8 + (q4 & 1) * 4];
                oacc[0][nb] = __builtin_amdgcn_mfma_f32_16x16x16f16(ph[0][cb], vf, oacc[0][nb], 0, 0, 0);
                oacc[1][nb] = __builtin_amdgcn_mfma_f32_16x16x16f16(ph[1][cb], vf, oacc[1][nb], 0, 0, 0);
            }
            pacc[0] = __builtin_amdgcn_mfma_f32_16x16x16f16(ph[0][cb], vones, pacc[0], 0, 0, 0);
            pacc[1] = __builtin_amdgcn_mfma_f32_16x16x16f16(ph[1][cb], vones, pacc[1], 0, 0, 0);
        }
    }
    __syncthreads();   // all compute done before combine overlay reuses tiles

    // combine K-halves via LDS overlay (odd stride -> bank-permuting)
    float* Cb = (float*)&Tiles[0][0][0][0];
    const int crow = (wq * 64 + lane) * CSTR;
    if (kh == 1) {
#pragma unroll
        for (int nq = 0; nq < 2; nq++) {
#pragma unroll
            for (int nb = 0; nb < 4; nb++)
                *(f32x4*)&Cb[crow + (nq * 5 + nb) * 4] = oacc[nq][nb];
            *(f32x4*)&Cb[crow + (nq * 5 + 4) * 4] = pacc[nq];
        }
    }
    __syncthreads();
    if (kh == 0) {
#pragma unroll
        for (int nq = 0; nq < 2; nq++) {
#pragma unroll
            for (int nb = 0; nb < 4; nb++)
                oacc[nq][nb] += *(const f32x4*)&Cb[crow + (nq * 5 + nb) * 4];
            pacc[nq] += *(const f32x4*)&Cb[crow + (nq * 5 + 4) * 4];
        }
        // normalizer pacc[nq][r] sits at the same (q4,r) slot as O rows
#pragma unroll
        for (int nq = 0; nq < 2; nq++)
#pragma unroll
            for (int r = 0; r < 4; r++) {
                const float inv = 1.f / pacc[nq][r];
                const int s = q0 + wq * 32 + nq * 16 + q4 * 4 + r;
#pragma unroll
                for (int nb = 0; nb < 4; nb++)
                    Ow[((size_t)b * SEQ + s) * HIDDEN + h * HD + nb * 16 + l15] =
                        to_bf16(oacc[nq][nb][r] * inv);
            }
    }
}

// ---------------- output projection: 64x128 tile, BK=64, C^T fragments ------
__global__ __launch_bounds__(256, 2) void oproj_kernel(
    const bf16_t* __restrict__ A, const bf16_t* __restrict__ Wo,
    const float* __restrict__ bo, float* __restrict__ Out)
{
    __shared__ __align__(16) bf16_t As[64 * 64];
    __shared__ __align__(16) bf16_t Bs[128 * 64];
    const int m0 = blockIdx.y * 64, n0 = blockIdx.x * 128;
    const int t = threadIdx.x, lane = t & 63, w = t >> 6;
    const int l15 = lane & 15, q4 = lane >> 4;

    f32x4 acc[4][2];
#pragma unroll
    for (int i = 0; i < 4; i++)
#pragma unroll
        for (int j = 0; j < 2; j++) acc[i][j] = f32x4{0.f, 0.f, 0.f, 0.f};

    for (int kt = 0; kt < HIDDEN; kt += 64) {
#pragma unroll
        for (int j = 0; j < 2; j++) {
            const int s = j * 256 + t;
            const int row = s >> 3, c = (s & 7) ^ (row & 7);
            async16(&A[(size_t)(m0 + row) * HIDDEN + kt + c * 8], &As[(j * 256 + w * 64) * 8]);
        }
#pragma unroll
        for (int j = 0; j < 4; j++) {
            const int s = j * 256 + t;
            const int row = s >> 3, c = (s & 7) ^ (row & 7);
            async16(&Wo[(size_t)(n0 + row) * HIDDEN + kt + c * 8], &Bs[(j * 256 + w * 64) * 8]);
        }
        __syncthreads();
#pragma unroll
        for (int ks = 0; ks < 2; ks++) {
            bf16x8 af[4];
#pragma unroll
            for (int ti = 0; ti < 4; ti++) {
                const int ra = ti * 16 + l15;
                af[ti] = *(const bf16x8*)&As[ra * 64 + (((ks * 4 + q4) ^ (ra & 7))) * 8];
            }
#pragma unroll
            for (int tj = 0; tj < 2; tj++) {
                const int rb = w * 32 + tj * 16 + l15;
                const bf16x8 bfr = *(const bf16x8*)&Bs[rb * 64 + (((ks * 4 + q4) ^ (rb & 7))) * 8];
                // swapped operands: acc holds C^T fragments (4 consecutive n per reg)
#pragma unroll
                for (int ti = 0; ti < 4; ti++)
                    acc[ti][tj] = __builtin_amdgcn_mfma_f32_16x16x32_bf16(bfr, af[ti], acc[ti][tj], 0, 0, 0);
            }
        }
        __syncthreads();
    }

    // C[m = m0+ti*16+l15][n = n0+w*32+tj*16+q4*4+r] -> f32x4 stores
#pragma unroll
    for (int tj = 0; tj < 2; tj++) {
        const int nb4 = n0 + w * 32 + tj * 16 + q4 * 4;
        const float4 bb = *(const float4*)&bo[nb4];
#pragma unroll
        for (int ti = 0; ti < 4; ti++) {
            const int m = m0 + ti * 16 + l15;
            float4 ov;
            ov.x = acc[ti][tj][0] + bb.x;
            ov.y = acc[ti][tj][1] + bb.y;
            ov.z = acc[ti][tj][2] + bb.z;
            ov.w = acc[ti][tj][3] + bb.w;
            *(float4*)&Out[(size_t)m * HIDDEN + nb4] = ov;
        }
    }
}

extern "C" void kernel_launch(void* const* d_in, const int* in_sizes, int n_in,
                              void* d_out, int out_size, void* d_ws, size_t ws_size,
                              hipStream_t stream) {
    const float* X   = (const float*)d_in[0];
    const float* msk = (const float*)d_in[1];
    const float* wq  = (const float*)d_in[2];
    const float* bq  = (const float*)d_in[3];
    const float* wk  = (const float*)d_in[4];
    const float* bk  = (const float*)d_in[5];
    const float* wv  = (const float*)d_in[6];
    const float* bv  = (const float*)d_in[7];
    const float* wo  = (const float*)d_in[8];
    const float* bo  = (const float*)d_in[9];
    float* out = (float*)d_out;

    const size_t NELT = (size_t)2 * SEQ * HIDDEN;  // 4M
    const size_t WELT = (size_t)HIDDEN * HIDDEN;   // 1M
    bf16_t*    xbf = (bf16_t*)d_ws;     // [B,S,1024] bf16
    bf16_t*    qws = xbf + NELT;        // [B,S,1024] (Q)
    bf16_t*    kws = qws + NELT;        // [B,S,1024] (K)
    _Float16*  vws = (_Float16*)(kws + NELT);  // [B,H,64,S] fp16 (V^T)
    bf16_t*    aws = xbf;               // attn out aliases xbf (dead after qkv)
    bf16_t*    wqb = (bf16_t*)d_out;    // weight scratch in d_out (written last)
    bf16_t*    wkb = wqb + WELT;
    bf16_t*    wvb = wkb + WELT;
    bf16_t*    wob = wvb + WELT;        // 8 MB total <= 16 MB d_out

    cvt_kernel<<<dim3(2048 + 4 * 512), dim3(256), 0, stream>>>(
        X, xbf, 2048, wq, wqb, 512, wk, wkb, 512, wv, wvb, 512, wo, wob, 512);
    qkv_kernel<<<dim3(8, 32, 3), dim3(256), 0, stream>>>(
        xbf, wqb, wkb, wvb, bq, bk, bv, qws, kws, vws);
    attn_kernel<<<dim3(1024), dim3(256), 0, stream>>>(qws, kws, vws, msk, aws);
    oproj_kernel<<<dim3(8, 64), dim3(256), 0, stream>>>(aws, wob, bo, out);
}

// Round 9
// 208.429 us; speedup vs baseline: 1.0096x; 1.0096x over previous
//
#include <hip/hip_runtime.h>
#include <hip/hip_bf16.h>

typedef __bf16 bf16_t;
typedef __bf16 bf16x8 __attribute__((ext_vector_type(8)));
typedef _Float16 f16x4 __attribute__((ext_vector_type(4)));
typedef _Float16 f16x8 __attribute__((ext_vector_type(8)));
typedef float f32x4 __attribute__((ext_vector_type(4)));

#define SEQ    2048
#define NH     16
#define HD     64
#define HIDDEN 1024
#define LOG2E  1.44269504f
#define CSTR   41   // combine overlay stride (odd -> bank-permuting)

__device__ __forceinline__ bf16_t to_bf16(float f) { return (bf16_t)f; }

// async 16B global->LDS DMA; LDS dest is wave-uniform base, HW adds lane*16.
__device__ __forceinline__ void async16(const void* g, void* l) {
    __builtin_amdgcn_global_load_lds((const __attribute__((address_space(1))) void*)g,
                                     (__attribute__((address_space(3))) void*)l, 16, 0, 0);
}

// ---------------- fp32 -> bf16 convert (5 segments, one launch) ----------------
__global__ __launch_bounds__(256) void cvt_kernel(
    const float* __restrict__ s0, bf16_t* __restrict__ d0, int c0,
    const float* __restrict__ s1, bf16_t* __restrict__ d1, int c1,
    const float* __restrict__ s2, bf16_t* __restrict__ d2, int c2,
    const float* __restrict__ s3, bf16_t* __restrict__ d3, int c3,
    const float* __restrict__ s4, bf16_t* __restrict__ d4, int c4)
{
    int blk = blockIdx.x;
    const float* s; bf16_t* d;
    if (blk < c0)              { s = s0; d = d0; }
    else if ((blk -= c0) < c1) { s = s1; d = d1; }
    else if ((blk -= c1) < c2) { s = s2; d = d2; }
    else if ((blk -= c2) < c3) { s = s3; d = d3; }
    else                       { blk -= c3; s = s4; d = d4; }
    const size_t base = (size_t)blk * 2048 + threadIdx.x * 8;
    const float4 a = *(const float4*)&s[base];
    const float4 b = *(const float4*)&s[base + 4];
    bf16x8 o;
    o[0] = (bf16_t)a.x; o[1] = (bf16_t)a.y; o[2] = (bf16_t)a.z; o[3] = (bf16_t)a.w;
    o[4] = (bf16_t)b.x; o[5] = (bf16_t)b.y; o[6] = (bf16_t)b.z; o[7] = (bf16_t)b.w;
    *(bf16x8*)&d[base] = o;
}

// ---------------- QKV projection: 128x128 tile, BK=32 DOUBLE-BUFFERED --------
// z=0:Q, z=1:K -> [B,S,1024] bf16; z=2:V -> [B,H,64,S] fp16 (PV B-operand)
__global__ __launch_bounds__(256, 3) void qkv_kernel(
    const bf16_t* __restrict__ X,
    const bf16_t* __restrict__ wq, const bf16_t* __restrict__ wk, const bf16_t* __restrict__ wv,
    const float* __restrict__ bq, const float* __restrict__ bk, const float* __restrict__ bv,
    bf16_t* __restrict__ qws, bf16_t* __restrict__ kws, _Float16* __restrict__ vws)
{
    // 32 KB: [buf][A 4096 | B 4096] staging; reused as 128x128 epilogue tile
    __shared__ __align__(16) bf16_t Sh[16384];
    const int z = blockIdx.z;
    const bf16_t* Wsel = (z == 0) ? wq : (z == 1) ? wk : wv;
    const float*  bsel = (z == 0) ? bq : (z == 1) ? bk : bv;
    const int m0 = blockIdx.y * 128, n0 = blockIdx.x * 128;

    const int t = threadIdx.x, lane = t & 63, w = t >> 6;
    const int w0 = w & 1, w1 = w >> 1, l15 = lane & 15, q4 = lane >> 4;

    f32x4 acc[4][4];
#pragma unroll
    for (int i = 0; i < 4; i++)
#pragma unroll
        for (int j = 0; j < 4; j++) acc[i][j] = f32x4{0.f, 0.f, 0.f, 0.f};

    auto stage = [&](int kt, int buf) {
#pragma unroll
        for (int j = 0; j < 2; j++) {
            const int s = j * 256 + t;              // 16B slot 0..511
            const int row = s >> 2, c = (s & 3) ^ (row & 3);
            const int lb = buf * 8192 + (j * 256 + w * 64) * 8;
            async16(&X[(size_t)(m0 + row) * HIDDEN + kt + c * 8], &Sh[lb]);
            async16(&Wsel[(size_t)(n0 + row) * HIDDEN + kt + c * 8], &Sh[lb + 4096]);
        }
    };
    stage(0, 0);

    for (int it = 0; it < 32; it++) {
        const int cur = it & 1;
        __syncthreads();                            // buf[cur] ready; buf[cur^1] free
        if (it < 31) stage((it + 1) * 32, cur ^ 1);
        const bf16_t* As = &Sh[cur * 8192];
        const bf16_t* Bs = &Sh[cur * 8192 + 4096];
        bf16x8 af[4];
#pragma unroll
        for (int ti = 0; ti < 4; ti++) {
            const int ra = w0 * 64 + ti * 16 + l15;
            af[ti] = *(const bf16x8*)&As[ra * 32 + (q4 ^ (ra & 3)) * 8];
        }
#pragma unroll
        for (int tj = 0; tj < 4; tj++) {
            const int rb = w1 * 64 + tj * 16 + l15;
            const bf16x8 bfr = *(const bf16x8*)&Bs[rb * 32 + (q4 ^ (rb & 3)) * 8];
#pragma unroll
            for (int ti = 0; ti < 4; ti++)
                acc[ti][tj] = __builtin_amdgcn_mfma_f32_16x16x32_bf16(af[ti], bfr, acc[ti][tj], 0, 0, 0);
        }
    }
    __syncthreads();

    // ---- epilogue: acc -> LDS tile (swizzled) -> coalesced b128 stores ----
    if (z < 2) {
        // LDS [m][n] bf16 128x128; chunk(8 elems) XOR-swizzled by m
#pragma unroll
        for (int tj = 0; tj < 4; tj++) {
            const int n = w1 * 64 + tj * 16 + l15;
            const float bb = bsel[n0 + n];
            const int ch = (n >> 3), sub = n & 7;
#pragma unroll
            for (int ti = 0; ti < 4; ti++)
#pragma unroll
                for (int r = 0; r < 4; r++) {
                    const int m = w0 * 64 + ti * 16 + q4 * 4 + r;
                    Sh[m * 128 + ((ch ^ (m & 15)) << 3) + sub] = to_bf16(acc[ti][tj][r] + bb);
                }
        }
        __syncthreads();
        bf16_t* dst = (z == 0) ? qws : kws;
#pragma unroll
        for (int i = 0; i < 8; i++) {
            const int g = i * 256 + t;
            const int row = g >> 4, c = g & 15;
            const bf16x8 vv = *(const bf16x8*)&Sh[row * 128 + ((c ^ (row & 15)) << 3)];
            *(bf16x8*)&dst[(size_t)(m0 + row) * HIDDEN + n0 + c * 8] = vv;
        }
    } else {
        // LDS [n(d)][m(s)] f16 128x128 (transpose in LDS)
        _Float16* Vt = (_Float16*)Sh;
#pragma unroll
        for (int tj = 0; tj < 4; tj++) {
            const int n = w1 * 64 + tj * 16 + l15;
            const float bb = bsel[n0 + n];
#pragma unroll
            for (int ti = 0; ti < 4; ti++) {
                const int mb = w0 * 64 + ti * 16 + q4 * 4;
                f16x4 v;
#pragma unroll
                for (int r = 0; r < 4; r++) v[r] = (_Float16)(acc[ti][tj][r] + bb);
                *(f16x4*)&Vt[n * 128 + (((mb >> 3) ^ (n & 15)) << 3) + (mb & 7)] = v;
            }
        }
        __syncthreads();
        const int b = m0 >> 11, sbase = m0 & (SEQ - 1);
#pragma unroll
        for (int i = 0; i < 8; i++) {
            const int g = i * 256 + t;
            const int row = g >> 4, c = g & 15;       // row = d-col, c = s-chunk
            const f16x8 vv = *(const f16x8*)&Vt[row * 128 + ((c ^ (row & 15)) << 3)];
            const int d = (n0 + row) & 63, hh = (n0 + row) >> 6;
            *(f16x8*)&vws[(((size_t)b * NH + hh) * HD + d) * SEQ + sbase + c * 8] = vv;
        }
    }
}

// ---------------- flash attention: S^T registers, VALU psum (r4-best) --------
// grid 1024: 32 bh x 32 q-tiles(64). Block 256 = 4 waves:
// wave w: q-sub (w&1)*32, K-half (w>>1)*1024. No P LDS round-trip.
__global__ __launch_bounds__(256, 4) void attn_kernel(
    const bf16_t* __restrict__ Qw, const bf16_t* __restrict__ Kw,
    const _Float16* __restrict__ Vtw, const float* __restrict__ Mask,
    bf16_t* __restrict__ Ow)
{
    __shared__ __align__(16) bf16_t Tiles[2][2][64 * 64];   // [khalf][K|V] 32 KB

    const int t = threadIdx.x, lane = t & 63, w = t >> 6;
    const int l15 = lane & 15, q4 = lane >> 4;
    const int wq = w & 1, kh = w >> 1;
    // XCD swizzle: cluster 4 heads per XCD (K/V fit per-XCD L2)
    const int lid = blockIdx.x;
    const int c8 = lid & 7, j = lid >> 3;
    const int bh = c8 * 4 + (j >> 5);
    const int q0 = (j & 31) * 64;
    const int b = bh >> 4, h = bh & 15;

    const bf16_t* Qh = Qw + (size_t)b * SEQ * HIDDEN + h * HD;     // [s][1024]
    const bf16_t* Kh = Kw + (size_t)b * SEQ * HIDDEN + h * HD;
    const _Float16* Vh = Vtw + (size_t)bh * HD * SEQ;              // [64][SEQ]
    const float* Mrow = Mask + (size_t)b * SEQ;

    bf16x8 qf[2][2];
#pragma unroll
    for (int nq = 0; nq < 2; nq++)
#pragma unroll
        for (int ks = 0; ks < 2; ks++)
            qf[nq][ks] = *(const bf16x8*)&Qh[(size_t)(q0 + wq * 32 + nq * 16 + l15) * HIDDEN + ks * 32 + q4 * 8];

    f32x4 oacc[2][4];
#pragma unroll
    for (int nq = 0; nq < 2; nq++)
#pragma unroll
        for (int nb = 0; nb < 4; nb++) oacc[nq][nb] = f32x4{0.f, 0.f, 0.f, 0.f};
    float psum[2] = {0.f, 0.f};

    bf16_t* Ksh = &Tiles[kh][0][0];
    _Float16* Vsh = (_Float16*)&Tiles[kh][1][0];
    const int kbase = kh * (SEQ / 2);
    const int s0_ = wq * 64 + lane;

    for (int it = 0; it < 16; it++) {
        const int kt = kbase + it * 64;
#pragma unroll
        for (int jj = 0; jj < 4; jj++) {
            const int s = jj * 128 + s0_;
            const int row = s >> 3, c = (s & 7) ^ (row & 7);
            const int lbase = (jj * 128 + wq * 64) * 8;
            async16(&Kh[(size_t)(kt + row) * HIDDEN + c * 8], &Ksh[lbase]);
            async16(&Vh[(size_t)row * SEQ + kt + c * 8], &Vsh[lbase]);
        }
        __syncthreads();

        // S^T = K Q^T: lane(l15=q, q4) reg r -> kpos = cb*16 + q4*4 + r
        f32x4 sa[2][4];
#pragma unroll
        for (int nq = 0; nq < 2; nq++)
#pragma unroll
            for (int cb = 0; cb < 4; cb++) sa[nq][cb] = f32x4{0.f, 0.f, 0.f, 0.f};
#pragma unroll
        for (int cb = 0; cb < 4; cb++)
#pragma unroll
            for (int ks = 0; ks < 2; ks++) {
                const int rk = cb * 16 + l15;
                const bf16x8 kf = *(const bf16x8*)&Ksh[rk * 64 + (((ks * 4 + q4) ^ (rk & 7))) * 8];
                sa[0][cb] = __builtin_amdgcn_mfma_f32_16x16x32_bf16(kf, qf[0][ks], sa[0][cb], 0, 0, 0);
                sa[1][cb] = __builtin_amdgcn_mfma_f32_16x16x32_bf16(kf, qf[1][ks], sa[1][cb], 0, 0, 0);
            }

        // softmax numerator in-register; per-lane partial row sums (VALU)
        f16x4 ph[2][4];
#pragma unroll
        for (int cb = 0; cb < 4; cb++) {
            float4 mv = *(const float4*)&Mrow[kt + cb * 16 + q4 * 4];
            mv.x *= LOG2E; mv.y *= LOG2E; mv.z *= LOG2E; mv.w *= LOG2E;
            const float mk[4] = {mv.x, mv.y, mv.z, mv.w};
#pragma unroll
            for (int nq = 0; nq < 2; nq++) {
#pragma unroll
                for (int r = 0; r < 4; r++) {
                    const float p = exp2f(fmaf(sa[nq][cb][r], 0.125f * LOG2E, mk[r]));
                    psum[nq] += p;
                    ph[nq][cb][r] = (_Float16)p;
                }
            }
        }

        // PV: P registers are A-operand of 16x16x16f16
#pragma unroll
        for (int cb = 0; cb < 4; cb++) {
#pragma unroll
            for (int nb = 0; nb < 4; nb++) {
                const int rv = nb * 16 + l15;
                const int cl = (cb * 2 + (q4 >> 1)) ^ (rv & 7);
                const f16x4 vf = *(const f16x4*)&Vsh[rv * 64 + cl * 8 + (q4 & 1) * 4];
                oacc[0][nb] = __builtin_amdgcn_mfma_f32_16x16x16f16(ph[0][cb], vf, oacc[0][nb], 0, 0, 0);
                oacc[1][nb] = __builtin_amdgcn_mfma_f32_16x16x16f16(ph[1][cb], vf, oacc[1][nb], 0, 0, 0);
            }
        }
        __syncthreads();
    }

    // reduce psum across q4 groups (full K-half sum per q=l15)
#pragma unroll
    for (int nq = 0; nq < 2; nq++) {
        psum[nq] += __shfl_xor(psum[nq], 16);
        psum[nq] += __shfl_xor(psum[nq], 32);
    }

    // combine K-halves via LDS overlay (odd stride -> bank-permuting)
    float* Cb = (float*)&Tiles[0][0][0];
    const int crow = (wq * 64 + lane) * CSTR;
    if (kh == 1) {
#pragma unroll
        for (int nq = 0; nq < 2; nq++) {
#pragma unroll
            for (int nb = 0; nb < 4; nb++)
                *(f32x4*)&Cb[crow + (nq * 4 + nb) * 4] = oacc[nq][nb];
            Cb[crow + 32 + nq] = psum[nq];
        }
    }
    __syncthreads();
    if (kh == 0) {
#pragma unroll
        for (int nq = 0; nq < 2; nq++) {
#pragma unroll
            for (int nb = 0; nb < 4; nb++)
                oacc[nq][nb] += *(const f32x4*)&Cb[crow + (nq * 4 + nb) * 4];
            psum[nq] += Cb[crow + 32 + nq];
        }
        // normalize: O rows are q = q4*4 + r; psum lives at lane l15 = q
#pragma unroll
        for (int nq = 0; nq < 2; nq++) {
            float inv[4];
#pragma unroll
            for (int r = 0; r < 4; r++) inv[r] = 1.f / __shfl(psum[nq], q4 * 4 + r);
#pragma unroll
            for (int r = 0; r < 4; r++) {
                const int s = q0 + wq * 32 + nq * 16 + q4 * 4 + r;
#pragma unroll
                for (int nb = 0; nb < 4; nb++)
                    Ow[((size_t)b * SEQ + s) * HIDDEN + h * HD + nb * 16 + l15] =
                        to_bf16(oacc[nq][nb][r] * inv[r]);
            }
        }
    }
}

// ---------------- output projection: 64x128 tile, BK=32 dbuf, C^T frags -----
__global__ __launch_bounds__(256, 2) void oproj_kernel(
    const bf16_t* __restrict__ A, const bf16_t* __restrict__ Wo,
    const float* __restrict__ bo, float* __restrict__ Out)
{
    __shared__ __align__(16) bf16_t Sh[12288];   // 24 KB: [buf][A 2048 | B 4096]
    const int m0 = blockIdx.y * 64, n0 = blockIdx.x * 128;
    const int t = threadIdx.x, lane = t & 63, w = t >> 6;
    const int l15 = lane & 15, q4 = lane >> 4;

    f32x4 acc[4][2];
#pragma unroll
    for (int i = 0; i < 4; i++)
#pragma unroll
        for (int j = 0; j < 2; j++) acc[i][j] = f32x4{0.f, 0.f, 0.f, 0.f};

    auto stage = [&](int kt, int buf) {
        {   // A: 256 slots -> 1 instr
            const int row = t >> 2, c = (t & 3) ^ (row & 3);
            async16(&A[(size_t)(m0 + row) * HIDDEN + kt + c * 8], &Sh[buf * 6144 + w * 64 * 8]);
        }
#pragma unroll
        for (int j = 0; j < 2; j++) {   // B: 512 slots -> 2 instrs
            const int s = j * 256 + t;
            const int row = s >> 2, c = (s & 3) ^ (row & 3);
            async16(&Wo[(size_t)(n0 + row) * HIDDEN + kt + c * 8],
                    &Sh[buf * 6144 + 2048 + (j * 256 + w * 64) * 8]);
        }
    };
    stage(0, 0);

    for (int it = 0; it < 32; it++) {
        const int cur = it & 1;
        __syncthreads();
        if (it < 31) stage((it + 1) * 32, cur ^ 1);
        const bf16_t* As = &Sh[cur * 6144];
        const bf16_t* Bs = &Sh[cur * 6144 + 2048];
        bf16x8 af[4];
#pragma unroll
        for (int ti = 0; ti < 4; ti++) {
            const int ra = ti * 16 + l15;
            af[ti] = *(const bf16x8*)&As[ra * 32 + (q4 ^ (ra & 3)) * 8];
        }
#pragma unroll
        for (int tj = 0; tj < 2; tj++) {
            const int rb = w * 32 + tj * 16 + l15;
            const bf16x8 bfr = *(const bf16x8*)&Bs[rb * 32 + (q4 ^ (rb & 3)) * 8];
            // swapped operands: acc holds C^T fragments (4 consecutive n per reg)
#pragma unroll
            for (int ti = 0; ti < 4; ti++)
                acc[ti][tj] = __builtin_amdgcn_mfma_f32_16x16x32_bf16(bfr, af[ti], acc[ti][tj], 0, 0, 0);
        }
    }

    // C[m = m0+ti*16+l15][n = n0+w*32+tj*16+q4*4+r] -> f32x4 stores
#pragma unroll
    for (int tj = 0; tj < 2; tj++) {
        const int nb4 = n0 + w * 32 + tj * 16 + q4 * 4;
        const float4 bb = *(const float4*)&bo[nb4];
#pragma unroll
        for (int ti = 0; ti < 4; ti++) {
            const int m = m0 + ti * 16 + l15;
            float4 ov;
            ov.x = acc[ti][tj][0] + bb.x;
            ov.y = acc[ti][tj][1] + bb.y;
            ov.z = acc[ti][tj][2] + bb.z;
            ov.w = acc[ti][tj][3] + bb.w;
            *(float4*)&Out[(size_t)m * HIDDEN + nb4] = ov;
        }
    }
}

extern "C" void kernel_launch(void* const* d_in, const int* in_sizes, int n_in,
                              void* d_out, int out_size, void* d_ws, size_t ws_size,
                              hipStream_t stream) {
    const float* X   = (const float*)d_in[0];
    const float* msk = (const float*)d_in[1];
    const float* wq  = (const float*)d_in[2];
    const float* bq  = (const float*)d_in[3];
    const float* wk  = (const float*)d_in[4];
    const float* bk  = (const float*)d_in[5];
    const float* wv  = (const float*)d_in[6];
    const float* bv  = (const float*)d_in[7];
    const float* wo  = (const float*)d_in[8];
    const float* bo  = (const float*)d_in[9];
    float* out = (float*)d_out;

    const size_t NELT = (size_t)2 * SEQ * HIDDEN;  // 4M
    const size_t WELT = (size_t)HIDDEN * HIDDEN;   // 1M
    bf16_t*    xbf = (bf16_t*)d_ws;     // [B,S,1024] bf16
    bf16_t*    qws = xbf + NELT;        // [B,S,1024] (Q)
    bf16_t*    kws = qws + NELT;        // [B,S,1024] (K)
    _Float16*  vws = (_Float16*)(kws + NELT);  // [B,H,64,S] fp16 (V^T)
    bf16_t*    aws = xbf;               // attn out aliases xbf (dead after qkv)
    bf16_t*    wqb = (bf16_t*)d_out;    // weight scratch in d_out (written last)
    bf16_t*    wkb = wqb + WELT;
    bf16_t*    wvb = wkb + WELT;
    bf16_t*    wob = wvb + WELT;        // 8 MB total <= 16 MB d_out

    cvt_kernel<<<dim3(2048 + 4 * 512), dim3(256), 0, stream>>>(
        X, xbf, 2048, wq, wqb, 512, wk, wkb, 512, wv, wvb, 512, wo, wob, 512);
    qkv_kernel<<<dim3(8, 32, 3), dim3(256), 0, stream>>>(
        xbf, wqb, wkb, wvb, bq, bk, bv, qws, kws, vws);
    attn_kernel<<<dim3(1024), dim3(256), 0, stream>>>(qws, kws, vws, msk, aws);
    oproj_kernel<<<dim3(8, 64), dim3(256), 0, stream>>>(aws, wob, bo, out);
}